// Round 10
// baseline (289.906 us; speedup 1.0000x reference)
//
#include <hip/hip_runtime.h>

typedef __bf16 bf16_t;
typedef __bf16 bf16x8 __attribute__((ext_vector_type(8)));
typedef __bf16 bf16x4 __attribute__((ext_vector_type(4)));
typedef float  f32x4  __attribute__((ext_vector_type(4)));
typedef int    i32x4  __attribute__((ext_vector_type(4)));

#define B_      16
#define L_      2048
#define D_      128
#define QTB     128              // q rows per block = 8 waves x 16
#define NEGINF  (-1.0e9f)
#define SCALE   0.08838834764831845f   // 1/sqrt(128)

#define MFMA_BF16 __builtin_amdgcn_mfma_f32_16x16x32_bf16

// lgkm drain + block barrier (vm loads stay in flight across it)
#define BARRIER() do { asm volatile("s_waitcnt lgkmcnt(0)" ::: "memory"); \
                       __builtin_amdgcn_s_barrier(); } while (0)
#define WAIT_VM(N) asm volatile("s_waitcnt vmcnt(" #N ")" ::: "memory")

// 16B global -> LDS DMA (lane l writes lds_base + l*16; gsrc is per-lane)
__device__ __forceinline__ void gload16(const void* g, void* l) {
    __builtin_amdgcn_global_load_lds(
        (const __attribute__((address_space(1))) void*)g,
        (__attribute__((address_space(3))) void*)l, 16, 0, 0);
}

// ---------------------------------------------------------------------------
// Prep kernel: blocks 0..255  : V fp32 [B][L][D] -> bf16 VT [B][D][L]
//              blocks 256..511: K fp32 -> bf16 row-major
// ---------------------------------------------------------------------------
__global__ __launch_bounds__(256) void prep_kernel(
    const float* __restrict__ k, const float* __restrict__ v,
    bf16_t* __restrict__ kb, bf16_t* __restrict__ vt)
{
    __shared__ bf16_t tile[128 * 144];
    const int tid = threadIdx.x;
    const int bid = (int)blockIdx.x;

    if (bid < 256) {
        const int b  = bid >> 4;
        const int l0 = (bid & 15) * 128;
        #pragma unroll
        for (int it = 0; it < 16; ++it) {
            int idx = tid + it * 256;
            int row = idx >> 5;
            int dc4 = idx & 31;
            f32x4 x = __builtin_nontemporal_load(
                (const f32x4*)(v + ((size_t)b * L_ + l0 + row) * (size_t)D_ + dc4 * 4));
            #pragma unroll
            for (int i = 0; i < 4; ++i) tile[(dc4 * 4 + i) * 144 + row] = (bf16_t)x[i];
        }
        __syncthreads();
        #pragma unroll
        for (int it = 0; it < 8; ++it) {
            int idx = tid + it * 256;
            int d   = idx >> 4;
            int lc  = idx & 15;
            bf16x8 vec = *(const bf16x8*)&tile[d * 144 + lc * 8];
            *(bf16x8*)(vt + ((size_t)b * D_ + d) * (size_t)L_ + l0 + lc * 8) = vec;
        }
    } else {
        const int idx0 = (bid - 256) * 256 + tid;
        #pragma unroll
        for (int c = 0; c < 16; ++c) {
            int idx = idx0 + c * 65536;
            f32x4 x = __builtin_nontemporal_load((const f32x4*)(k + (size_t)idx * 4));
            bf16x4 o;
            #pragma unroll
            for (int i = 0; i < 4; ++i) o[i] = (bf16_t)x[i];
            *(bf16x4*)(kb + (size_t)idx * 4) = o;
        }
    }
}

// ---------------------------------------------------------------------------
// Main kernel (needs workspace): 256 blocks (1/CU), 8 waves, 128 q-rows.
// K/V staged by global_load_lds DMA into fragment-order LDS slabs (3-deep,
// counted vmcnt BEFORE the single per-chunk barrier). Mask reg-staged dist-2,
// packed to bits in mbits (persists; pass 2 reads no mask at all).
// ---------------------------------------------------------------------------
__global__ __launch_bounds__(512, 1) void sdpa_kernel(
    const float* __restrict__ q, const int* __restrict__ mask,
    const bf16_t* __restrict__ kb, const bf16_t* __restrict__ vt,
    float* __restrict__ out, float* __restrict__ attn)
{
    __shared__ char     Kst[3][8192];      // K slabs, fragment order
    __shared__ char     Vst[3][8192];      // V slabs, fragment order
    __shared__ unsigned mbits[64 * 128];   // 32KB packed mask [chunk][qrow]
    __shared__ bf16_t   plds[8][16][40];   // P bounce (per-wave)

    const int tid = threadIdx.x;
    const int w   = tid >> 6;
    const int l   = tid & 63;
    const int li  = l & 15;
    const int lg  = l >> 4;

    // XCD-chunked bijective swizzle (256 % 8 == 0): 2 whole batches per XCD
    const int bid  = (int)blockIdx.x;
    const int bid2 = (bid & 7) * 32 + (bid >> 3);
    const int b    = bid2 >> 4;
    const int qt   = bid2 & 15;
    const int qbase = qt * QTB;

    const size_t bq = (size_t)b * L_;

    const float*  qp  = q  + (bq + qbase) * (size_t)D_;
    const bf16_t* kbp = kb + bq * (size_t)D_;
    const bf16_t* vtp = vt + (size_t)b * D_ * (size_t)L_;
    float* attnrow = attn + (bq + qbase + (size_t)(w * 16 + li)) * (size_t)L_;
    float* outp    = out  + (bq + qbase) * (size_t)D_;

    // ---------------- Q B-fragments (pre-scaled by 1/temper)
    bf16x8 aq[4];
    #pragma unroll
    for (int ds = 0; ds < 4; ++ds) {
        const float* p = qp + (size_t)(w * 16 + li) * D_ + ds * 32 + lg * 8;
        f32x4 x0 = *(const f32x4*)p;
        f32x4 x1 = *(const f32x4*)(p + 4);
        bf16x8 a;
        #pragma unroll
        for (int u = 0; u < 4; ++u) {
            a[u]     = (bf16_t)(x0[u] * SCALE);
            a[4 + u] = (bf16_t)(x1[u] * SCALE);
        }
        aq[ds] = a;
    }

    // ---------------- DMA source addresses (per lane), fragment-order slabs
    // K slab unit u = w*64 + l -> (ds=w>>1, t=w&1, lg=(l>>4)&3, li=l&15):
    //   holds K[c*32 + t*16 + li][ds*32 + lg*8 .. +8]
    const bf16_t* kgsrc = kbp + (size_t)((w & 1) * 16 + li) * D_ + (w >> 1) * 32 + lg * 8;
    // V slab unit u = w*64 + l -> (dt=w, lg, li): V^T[w*16+li][c*32 + lg*8 .. +8]
    const bf16_t* vgsrc = vtp + (size_t)(w * 16 + li) * L_ + lg * 8;
    char* kldsw = (char*)Kst + (size_t)w * 1024;   // + sl*0? per-slab below
    char* vldsw = (char*)Vst + (size_t)w * 1024;

    auto gloadK = [&](int c, int sl) {
        gload16(kgsrc + (size_t)c * 32 * D_, (char*)Kst[sl] + w * 1024);
    };
    auto gloadV = [&](int c, int sl) {
        gload16(vgsrc + (size_t)c * 32, (char*)Vst[sl] + w * 1024);
    };
    (void)kldsw; (void)vldsw;

    // ---------------- mask staging: thread (mr = tid&127, wg = tid>>7)
    const int mr = tid & 127, wg = tid >> 7;
    const int* msrc = mask + (size_t)(bq + qbase + mr) * L_ + wg * 8;
    auto issueM = [&](int c, i32x4& m0, i32x4& m1) {
        m0 = __builtin_nontemporal_load((const i32x4*)(msrc + c * 32));
        m1 = __builtin_nontemporal_load((const i32x4*)(msrc + c * 32 + 4));
    };
    auto writeM = [&](int c, const i32x4& m0, const i32x4& m1) {
        unsigned by = (m0[0] != 0 ?   1u : 0u) | (m0[1] != 0 ?   2u : 0u)
                    | (m0[2] != 0 ?   4u : 0u) | (m0[3] != 0 ?   8u : 0u)
                    | (m1[0] != 0 ?  16u : 0u) | (m1[1] != 0 ?  32u : 0u)
                    | (m1[2] != 0 ?  64u : 0u) | (m1[3] != 0 ? 128u : 0u);
        ((char*)mbits)[c * 512 + mr * 4 + wg] = (char)by;
    };
    auto maskbyte = [&](int c) -> unsigned {
        unsigned word = mbits[c * 128 + w * 16 + li];
        return ((word >> (lg * 4)) & 0xFu) | (((word >> (16 + lg * 4)) & 0xFu) << 4);
    };

    // QK^T from fragment-order K slab
    auto qkt = [&](int sl, f32x4& a0, f32x4& a1) {
        const char* Ks = Kst[sl];
        const int bo = lg * 256 + li * 16;
        f32x4 r0 = {0.f,0.f,0.f,0.f}, r1 = {0.f,0.f,0.f,0.f};
        #pragma unroll
        for (int ds = 0; ds < 4; ++ds) {
            bf16x8 k0 = *(const bf16x8*)(Ks + (ds * 2 + 0) * 1024 + bo);
            r0 = MFMA_BF16(k0, aq[ds], r0, 0, 0, 0);
        }
        #pragma unroll
        for (int ds = 0; ds < 4; ++ds) {
            bf16x8 k1 = *(const bf16x8*)(Ks + (ds * 2 + 1) * 1024 + bo);
            r1 = MFMA_BF16(k1, aq[ds], r1, 0, 0, 0);
        }
        a0 = r0; a1 = r1;
    };

    // ================= PASS 1: online masked max/sum ========================
    float m_run = -3.4e38f, l_run = 0.f;
    {
        auto p1c = [&](int c, int sl) {
            f32x4 a0, a1;
            qkt(sl, a0, a1);
            const unsigned byte = maskbyte(c);
            float s0[4], s1[4];
            #pragma unroll
            for (int r = 0; r < 4; ++r) {
                s0[r] = a0[r] + (((byte >> r)       & 1u) ? 0.f : NEGINF);
                s1[r] = a1[r] + (((byte >> (4 + r)) & 1u) ? 0.f : NEGINF);
            }
            float mx = fmaxf(fmaxf(fmaxf(s0[0], s0[1]), fmaxf(s0[2], s0[3])),
                             fmaxf(fmaxf(s1[0], s1[1]), fmaxf(s1[2], s1[3])));
            mx = fmaxf(mx, m_run);
            float acc = 0.f;
            #pragma unroll
            for (int r = 0; r < 4; ++r)
                acc += __expf(s0[r] - mx) + __expf(s1[r] - mx);
            l_run = l_run * __expf(m_run - mx) + acc;
            m_run = mx;
        };

        i32x4 mA0{}, mA1{}, mB0{}, mB1{};
        // prologue: chunk0 K + masks 0,1; drain; barrier
        gloadK(0, 0);
        issueM(0, mA0, mA1);
        issueM(1, mB0, mB1);
        writeM(0, mA0, mA1);
        WAIT_VM(0);
        BARRIER();

        int s0i = 0, s1i = 1, s2i = 2;
        #pragma unroll 1
        for (int c = 0; c < 64; c += 2) {
            // half A: compute c
            gloadK((c + 1) & 63, s1i);
            issueM((c + 2) & 63, mA0, mA1);
            writeM((c + 1) & 63, mB0, mB1);
            WAIT_VM(5);
            BARRIER();
            p1c(c, s0i);
            // half B: compute c+1
            gloadK((c + 2) & 63, s2i);
            issueM((c + 3) & 63, mB0, mB1);
            writeM((c + 2) & 63, mA0, mA1);
            WAIT_VM(5);
            BARRIER();
            p1c(c + 1, s1i);
            int t = s0i; s0i = s2i; s2i = s1i; s1i = t;   // (s0,s1,s2) <- (s2,s0,s1)
        }
    }

    // merge m/sum across the 4 lane-groups (lanes li, li+16, li+32, li+48)
    #pragma unroll
    for (int off = 16; off < 64; off <<= 1) {
        float mo = __shfl_xor(m_run, off);
        float lo = __shfl_xor(l_run, off);
        float mn = fmaxf(m_run, mo);
        l_run = l_run * __expf(m_run - mn) + lo * __expf(mo - mn);
        m_run = mn;
    }
    const float inv_l = 1.f / l_run;

    // ================= PASS 2: recompute + attn write + PV ==================
    f32x4 pv[8];
    #pragma unroll
    for (int dt = 0; dt < 8; ++dt) pv[dt] = {0.f, 0.f, 0.f, 0.f};

    {
        auto p2c = [&](int c, int sl) {
            f32x4 a0, a1;
            qkt(sl, a0, a1);
            const unsigned byte = maskbyte(c);
            f32x4 o0, o1; bf16x4 pb0, pb1;
            #pragma unroll
            for (int r = 0; r < 4; ++r) {
                float sa = a0[r] + (((byte >> r)       & 1u) ? 0.f : NEGINF);
                float sb = a1[r] + (((byte >> (4 + r)) & 1u) ? 0.f : NEGINF);
                float p0 = __expf(sa - m_run);
                float p1 = __expf(sb - m_run);
                o0[r] = p0 * inv_l;  o1[r] = p1 * inv_l;
                pb0[r] = (bf16_t)p0; pb1[r] = (bf16_t)p1;
            }
            // C-layout -> A-frag via per-wave LDS bounce
            *(bf16x4*)&plds[w][li][lg * 4]      = pb0;
            *(bf16x4*)&plds[w][li][16 + lg * 4] = pb1;
            bf16x8 pa = *(const bf16x8*)&plds[w][li][lg * 8];
            const char* Vs = Vst[sl];
            const int bo = lg * 256 + li * 16;
            #pragma unroll
            for (int dt = 0; dt < 8; ++dt) {
                bf16x8 vbf = *(const bf16x8*)(Vs + dt * 1024 + bo);
                pv[dt] = MFMA_BF16(pa, vbf, pv[dt], 0, 0, 0);
            }
            // attn stores LAST (counted in vmcnt, never waited on)
            __builtin_nontemporal_store(o0, (f32x4*)(attnrow + c * 32 + lg * 4));
            __builtin_nontemporal_store(o1, (f32x4*)(attnrow + c * 32 + 16 + lg * 4));
        };

        BARRIER();                // all pass-1 slab reads complete
        gloadK(0, 0); gloadV(0, 0);
        WAIT_VM(0);
        BARRIER();

        int s0i = 0, s1i = 1, s2i = 2;
        #pragma unroll 1
        for (int c = 0; c < 64; c += 2) {
            gloadK((c + 1) & 63, s1i); gloadV((c + 1) & 63, s1i);
            WAIT_VM(4);
            BARRIER();
            p2c(c, s0i);
            gloadK((c + 2) & 63, s2i); gloadV((c + 2) & 63, s2i);
            WAIT_VM(4);
            BARRIER();
            p2c(c + 1, s1i);
            int t = s0i; s0i = s2i; s2i = s1i; s1i = t;
        }
    }

    // ---------------- Epilogue: out[q][d] = pv * inv_l[q]
    #pragma unroll
    for (int r = 0; r < 4; ++r) {
        const float il = __shfl(inv_l, lg * 4 + r);
        float* orow = outp + (size_t)(w * 16 + lg * 4 + r) * D_ + li;
        #pragma unroll
        for (int dt = 0; dt < 8; ++dt)
            __builtin_nontemporal_store(pv[dt][r] * il, orow + dt * 16);
    }
}

// ---------------------------------------------------------------------------
// Workspace-free fallback (slow, simple, correct): one block per q-row.
// ---------------------------------------------------------------------------
__global__ __launch_bounds__(256) void sdpa_fallback(
    const float* __restrict__ q, const float* __restrict__ k,
    const float* __restrict__ v, const int* __restrict__ mask,
    float* __restrict__ out, float* __restrict__ attn)
{
    __shared__ float sc[2048];
    __shared__ float red[2];
    const int tid = threadIdx.x;
    const int b   = blockIdx.x >> 11;
    const int qr  = blockIdx.x & 2047;

    const float* qrow = q + ((size_t)b * L_ + qr) * D_;
    const float* kbase = k + (size_t)b * L_ * D_;
    const float* vbase = v + (size_t)b * L_ * D_;
    const int*   mrow = mask + ((size_t)b * L_ + qr) * (size_t)L_;
    float* arow = attn + ((size_t)b * L_ + qr) * (size_t)L_;
    float* orow = out + ((size_t)b * L_ + qr) * D_;

    for (int j = tid; j < 2048; j += 256) {
        float s = 0.f;
        for (int d = 0; d < D_; ++d) s += qrow[d] * kbase[(size_t)j * D_ + d];
        s = s * SCALE + (mrow[j] ? 0.f : NEGINF);
        sc[j] = s;
    }
    __syncthreads();
    float m = -3.4e38f;
    for (int j = tid; j < 2048; j += 256) m = fmaxf(m, sc[j]);
    #pragma unroll
    for (int off = 32; off; off >>= 1) m = fmaxf(m, __shfl_xor(m, off));
    if ((tid & 63) == 0) red[0] = m;   // waves race but take max below
    __syncthreads();
    if (tid == 0) {
        float mm = -3.4e38f;
        for (int j = 0; j < 2048; ++j) mm = fmaxf(mm, sc[j]);
        red[0] = mm;
    }
    __syncthreads();
    m = red[0];
    float sum = 0.f;
    for (int j = tid; j < 2048; j += 256) { float e = __expf(sc[j] - m); sc[j] = e; sum += e; }
    #pragma unroll
    for (int off = 32; off; off >>= 1) sum += __shfl_xor(sum, off);
    if (tid == 0) red[1] = 0.f;
    __syncthreads();
    if ((tid & 63) == 0) atomicAdd(&red[1], sum);
    __syncthreads();
    const float il = 1.f / red[1];
    for (int j = tid; j < 2048; j += 256) arow[j] = sc[j] * il;
    __syncthreads();
    if (tid < 128) {
        float acc = 0.f;
        for (int j = 0; j < 2048; ++j) acc += sc[j] * vbase[(size_t)j * D_ + tid];
        orow[tid] = acc * il;
    }
}

extern "C" void kernel_launch(void* const* d_in, const int* in_sizes, int n_in,
                              void* d_out, int out_size, void* d_ws, size_t ws_size,
                              hipStream_t stream) {
    const float* q    = (const float*)d_in[0];
    const float* k    = (const float*)d_in[1];
    const float* v    = (const float*)d_in[2];
    const int*   mask = (const int*)d_in[3];

    float* out  = (float*)d_out;
    float* attn = out + (size_t)B_ * L_ * D_;

    const size_t VT_BYTES = (size_t)B_ * D_ * L_ * 2;   // 8 MB
    const size_t KB_BYTES = (size_t)B_ * L_ * D_ * 2;   // 8 MB
    const bool ws_ok = ws_size >= VT_BYTES + KB_BYTES;
    bf16_t* vt = (bf16_t*)d_ws;
    bf16_t* kb = (bf16_t*)((char*)d_ws + VT_BYTES);

    if (ws_ok) {
        hipLaunchKernelGGL(prep_kernel, dim3(512), dim3(256), 0, stream, k, v, kb, vt);
        hipLaunchKernelGGL(sdpa_kernel, dim3(256), dim3(512), 0, stream,
                           q, mask, kb, vt, out, attn);
    } else {
        hipLaunchKernelGGL(sdpa_fallback, dim3(B_ * L_), dim3(256), 0, stream,
                           q, k, v, mask, out, attn);
    }
}